// Round 1
// baseline (3485.411 us; speedup 1.0000x reference)
//
#include <hip/hip_runtime.h>

#define NB 512
#define T 128
#define NS 32
#define NC 16
#define NSC 48

// One block per batch element. 256 threads.
// Backward Riccati recursion (stores K,k to global ws), then forward rollout.
__global__ __launch_bounds__(256, 2)
void lqr_kernel(const float* __restrict__ x_init,
                const float* __restrict__ Q,
                const float* __restrict__ p,
                const float* __restrict__ A,
                const float* __restrict__ Bm,
                const float* __restrict__ c1,
                float* __restrict__ out_x,
                float* __restrict__ out_u,
                float* __restrict__ out_cost,
                float* __restrict__ Kws,
                float* __restrict__ kws)
{
    const int b = blockIdx.x;
    const int tid = threadIdx.x;

    __shared__ float sF[NS][NSC + 1];    // F = [A | Bm], 32x48
    __shared__ float sV[NS][NS + 1];     // value matrix
    __shared__ float sW[NS][NSC + 1];    // W = V @ F
    __shared__ float sQt[NSC][NSC + 1];  // Qt = Q + F^T W
    __shared__ float sGJ[NC][NSC + 2];   // GJ augmented [Quu | Qux | qu], 16x49 used
    __shared__ float sv[NS];
    __shared__ float sz[NS];             // z = v + V c1
    __shared__ float sqt[NSC];
    __shared__ float sc1v[NS];
    __shared__ float sKt[NC][NS + 1];
    __shared__ float skt[NC];
    __shared__ float sM[NC][NS + 1];     // M = Quu @ Kt
    __shared__ float sr2[NC];            // r2 = qu + Quu kt
    __shared__ float sx[NSC];            // [x; u] in forward
    __shared__ float sred[4];

    // ---- init: load F, c1; V=0, v=0 ----
    for (int e = tid; e < NS * NSC; e += 256) {
        int i = e / NSC, j = e % NSC;
        float val = (j < NS) ? A[(size_t)b * NS * NS + i * NS + j]
                             : Bm[(size_t)b * NS * NC + i * NC + (j - NS)];
        sF[i][j] = val;
    }
    for (int e = tid; e < NS * NS; e += 256) sV[e / NS][e % NS] = 0.f;
    if (tid < NS) { sv[tid] = 0.f; sc1v[tid] = c1[(size_t)b * NS + tid]; }
    __syncthreads();

    // ================= backward pass =================
    for (int t = T - 1; t >= 0; --t) {
        const float* Qg = Q + ((size_t)b * T + t) * NSC * NSC;
        const float* pg = p + ((size_t)b * T + t) * NSC;

        // P1: W = V @ F ; z = v + V @ c1
        {
            int i = tid >> 3;      // 0..31
            int g = tid & 7;       // 0..7
            int j0 = g * 6;
            float acc[6] = {0, 0, 0, 0, 0, 0};
            for (int k = 0; k < NS; ++k) {
                float vik = sV[i][k];
                #pragma unroll
                for (int jj = 0; jj < 6; ++jj)
                    acc[jj] += vik * sF[k][j0 + jj];
            }
            #pragma unroll
            for (int jj = 0; jj < 6; ++jj) sW[i][j0 + jj] = acc[jj];
            if (tid < NS) {
                float a = sv[tid];
                for (int k = 0; k < NS; ++k) a += sV[tid][k] * sc1v[k];
                sz[tid] = a;
            }
        }
        __syncthreads();

        // P2: Qt = Q + F^T W (3x3 register tiles); qt = p + F^T z; fold GJ build
        {
            int rg = tid >> 4, cg = tid & 15;
            int i0 = rg * 3, j0 = cg * 3;
            float acc[3][3];
            #pragma unroll
            for (int a2 = 0; a2 < 3; a2++)
                #pragma unroll
                for (int b2 = 0; b2 < 3; b2++)
                    acc[a2][b2] = Qg[(i0 + a2) * NSC + (j0 + b2)];
            for (int k = 0; k < NS; ++k) {
                float f0 = sF[k][i0], f1 = sF[k][i0 + 1], f2 = sF[k][i0 + 2];
                float w0 = sW[k][j0], w1 = sW[k][j0 + 1], w2 = sW[k][j0 + 2];
                acc[0][0] += f0 * w0; acc[0][1] += f0 * w1; acc[0][2] += f0 * w2;
                acc[1][0] += f1 * w0; acc[1][1] += f1 * w1; acc[1][2] += f1 * w2;
                acc[2][0] += f2 * w0; acc[2][1] += f2 * w1; acc[2][2] += f2 * w2;
            }
            #pragma unroll
            for (int a2 = 0; a2 < 3; a2++)
                #pragma unroll
                for (int b2 = 0; b2 < 3; b2++) {
                    int i = i0 + a2, j = j0 + b2;
                    float v = acc[a2][b2];
                    sQt[i][j] = v;
                    if (i >= NS) {
                        int r = i - NS;
                        int c = (j >= NS) ? (j - NS) : (NC + j);
                        sGJ[r][c] = v;
                    }
                }
            if (tid < NSC) {
                float a = pg[tid];
                for (int k = 0; k < NS; ++k) a += sF[k][tid] * sz[k];
                sqt[tid] = a;
                if (tid >= NS) sGJ[tid - NS][NSC] = a;  // qu at col 48
            }
        }
        __syncthreads();

        // P4: Gauss-Jordan elimination, 16 pivots, ONE barrier per pivot.
        // Within a step: reads touch row kpiv and column kpiv only (never
        // written this step); writes touch rows i!=kpiv, cols j>kpiv.
        for (int kpiv = 0; kpiv < NC; ++kpiv) {
            float inv = 1.0f / sGJ[kpiv][kpiv];
            for (int e = tid; e < NC * 49; e += 256) {
                int i = e / 49, j = e % 49;
                if (i != kpiv && j > kpiv) {
                    sGJ[i][j] -= sGJ[i][kpiv] * inv * sGJ[kpiv][j];
                }
            }
            __syncthreads();
        }

        // P5: extract Kt = -Quu^-1 Qux, kt = -Quu^-1 qu; write to ws
        {
            float* Kg = Kws + ((size_t)b * T + t) * NC * NS;
            for (int e = tid; e < NC * NS; e += 256) {
                int r = e / NS, j = e % NS;
                float val = -sGJ[r][NC + j] / sGJ[r][r];
                sKt[r][j] = val;
                Kg[e] = val;
            }
            if (tid < NC) {
                float val = -sGJ[tid][NSC] / sGJ[tid][tid];
                skt[tid] = val;
                kws[((size_t)b * T + t) * NC + tid] = val;
            }
        }
        __syncthreads();

        // P6: M = Quu @ Kt ; r2 = qu + Quu @ kt
        {
            for (int e = tid; e < NC * NS; e += 256) {
                int r = e / NS, j = e % NS;
                float a = 0.f;
                #pragma unroll
                for (int l = 0; l < NC; ++l)
                    a += sQt[NS + r][NS + l] * sKt[l][j];
                sM[r][j] = a;
            }
            if (tid < NC) {
                float a = sqt[NS + tid];
                #pragma unroll
                for (int l = 0; l < NC; ++l)
                    a += sQt[NS + tid][NS + l] * skt[l];
                sr2[tid] = a;
            }
        }
        __syncthreads();

        // P7: V = Qxx + Qxu@Kt + Kt^T (Qux + M) ; v = qx + Qxu@kt + Kt^T r2
        // (sV/sv no longer read this iteration -> write in place)
        {
            for (int e = tid; e < NS * NS; e += 256) {
                int i = e / NS, j = e % NS;
                float a = sQt[i][j];
                #pragma unroll
                for (int k = 0; k < NC; ++k) {
                    a += sQt[i][NS + k] * sKt[k][j];
                    a += sKt[k][i] * (sQt[NS + k][j] + sM[k][j]);
                }
                sV[i][j] = a;
            }
            if (tid < NS) {
                float a = sqt[tid];
                #pragma unroll
                for (int k = 0; k < NC; ++k) {
                    a += sQt[tid][NS + k] * skt[k];
                    a += sKt[k][tid] * sr2[k];
                }
                sv[tid] = a;
            }
        }
        __syncthreads();
    }

    // ================= forward pass =================
    float xn_reg = 0.f;
    if (tid < NS) xn_reg = x_init[(size_t)b * NS + tid];
    float costAcc = 0.f;

    for (int t = 0; t < T; ++t) {
        // A: load K,k tile; publish current x
        const float* Kg = Kws + ((size_t)b * T + t) * NC * NS;
        for (int e = tid; e < NC * NS; e += 256) sKt[e / NS][e % NS] = Kg[e];
        if (tid < NC) skt[tid] = kws[((size_t)b * T + t) * NC + tid];
        if (tid < NS) sx[tid] = xn_reg;
        __syncthreads();

        // B: u = K x + k
        if (tid < NC) {
            float u = skt[tid];
            #pragma unroll
            for (int j = 0; j < NS; ++j) u += sKt[tid][j] * sx[j];
            sx[NS + tid] = u;
        }
        __syncthreads();

        // C: cost partial (0.5 xu^T Q xu + p.xu), outputs, x_next
        const float* Qg = Q + ((size_t)b * T + t) * NSC * NSC;
        const float* pg = p + ((size_t)b * T + t) * NSC;
        for (int e = tid; e < NSC * NSC; e += 256) {
            int i = e / NSC, j = e % NSC;
            costAcc += 0.5f * Qg[e] * sx[i] * sx[j];
        }
        if (tid < NSC) costAcc += pg[tid] * sx[tid];
        if (tid < NS) out_x[((size_t)b * T + t) * NS + tid] = sx[tid];
        else if (tid < NSC) out_u[((size_t)b * T + t) * NC + (tid - NS)] = sx[tid];
        if (tid < NS) {
            float a = sc1v[tid];
            #pragma unroll
            for (int j = 0; j < NSC; ++j) a += sF[tid][j] * sx[j];
            xn_reg = a;   // x_{t+1}, published next iteration
        }
        __syncthreads();
    }

    // block-reduce costAcc
    for (int off = 32; off > 0; off >>= 1)
        costAcc += __shfl_down(costAcc, off, 64);
    int wave = tid >> 6;
    if ((tid & 63) == 0) sred[wave] = costAcc;
    __syncthreads();
    if (tid == 0) out_cost[b] = sred[0] + sred[1] + sred[2] + sred[3];
}

extern "C" void kernel_launch(void* const* d_in, const int* in_sizes, int n_in,
                              void* d_out, int out_size, void* d_ws, size_t ws_size,
                              hipStream_t stream) {
    const float* x_init = (const float*)d_in[0];
    const float* Q      = (const float*)d_in[1];
    const float* p      = (const float*)d_in[2];
    const float* A      = (const float*)d_in[3];
    const float* Bm     = (const float*)d_in[4];
    const float* c1     = (const float*)d_in[5];

    float* out      = (float*)d_out;
    float* out_x    = out;                                  // NB*T*NS
    float* out_u    = out + (size_t)NB * T * NS;            // NB*T*NC
    float* out_cost = out + (size_t)NB * T * (NS + NC);     // NB

    float* Kws = (float*)d_ws;                              // NB*T*NC*NS floats
    float* kws = Kws + (size_t)NB * T * NC * NS;            // NB*T*NC floats

    lqr_kernel<<<NB, 256, 0, stream>>>(x_init, Q, p, A, Bm, c1,
                                       out_x, out_u, out_cost, Kws, kws);
}

// Round 2
// 2067.129 us; speedup vs baseline: 1.6861x; 1.6861x over previous
//
#include <hip/hip_runtime.h>

#define NB 512
#define T 128
#define NS 32
#define NC 16
#define NSC 48
#define PQ 52   // pad stride for sF, sW, sQt (52*4=208B, 16B-aligned rows)
#define PV 36   // pad stride for sV (144B rows)
#define PK 36   // pad stride for sKt

__device__ __forceinline__ float4 ld4(const float* p) { return *(const float4*)p; }
__device__ __forceinline__ void st4(float* p, float4 v) { *(float4*)p = v; }
__device__ __forceinline__ void fma4(float4& a, float s, float4 f) {
    a.x = fmaf(s, f.x, a.x); a.y = fmaf(s, f.y, a.y);
    a.z = fmaf(s, f.z, a.z); a.w = fmaf(s, f.w, a.w);
}
__device__ __forceinline__ float dot4(float4 a, float4 b) {
    return fmaf(a.x, b.x, fmaf(a.y, b.y, fmaf(a.z, b.z, a.w * b.w)));
}

// One block (256 threads) per batch element.
__global__ __launch_bounds__(256, 2)
void lqr_kernel(const float* __restrict__ x_init,
                const float* __restrict__ Q,
                const float* __restrict__ p,
                const float* __restrict__ A,
                const float* __restrict__ Bm,
                const float* __restrict__ c1,
                float* __restrict__ out_x,
                float* __restrict__ out_u,
                float* __restrict__ out_cost,
                float* __restrict__ Kws,
                float* __restrict__ kws)
{
    const int b = blockIdx.x;
    const int tid = threadIdx.x;
    const int lane = tid & 63;
    const int wv = tid >> 6;

    __shared__ __align__(16) float sF[NS][PQ];     // F = [A | Bm]
    __shared__ __align__(16) float sW[NS][PQ];     // W = V @ F
    __shared__ __align__(16) float sQt[NSC][PQ];   // Qt = Qg + F^T W
    __shared__ __align__(16) float sQg[NSC * NSC]; // prefetched Q tile (no pad)
    __shared__ __align__(16) float sV[NS][PV];
    __shared__ __align__(16) float sKt[NC][PK];
    __shared__ __align__(16) float sv[NS];
    __shared__ __align__(16) float sz[NS];
    __shared__ __align__(16) float sqt[NSC];
    __shared__ __align__(16) float sc1[NS];
    __shared__ __align__(16) float skt[NC];
    __shared__ __align__(16) float sx[NSC];
    __shared__ float sred[4];

    // ---------- init ----------
    for (int e = tid; e < NS * NSC; e += 256) {
        int i = e / NSC, j = e % NSC;
        sF[i][j] = (j < NS) ? A[(size_t)b * NS * NS + i * NS + j]
                            : Bm[(size_t)b * NS * NC + i * NC + (j - NS)];
    }
    for (int e = tid; e < NS * NS; e += 256) sV[e >> 5][e & 31] = 0.f;
    if (tid < NS) { sv[tid] = 0.f; sc1[tid] = c1[(size_t)b * NS + tid]; }
    {   // prefetch Q(t = T-1)
        const float4* Qg4 = (const float4*)(Q + ((size_t)b * T + (T - 1)) * NSC * NSC);
        float4* dst = (float4*)sQg;
        for (int r = tid; r < 576; r += 256) dst[r] = Qg4[r];
    }
    __syncthreads();

    // ---------- backward Riccati ----------
    for (int t = T - 1; t >= 0; --t) {
        // ---- Phase 1: wave0: W = V@F (2x12 tiles); wave1: z = v + V c1 ----
        if (wv == 0) {
            const int i0 = (lane >> 2) * 2;
            const int j0 = (lane & 3) * 12;
            float4 zz = {0.f, 0.f, 0.f, 0.f};
            float4 a00 = zz, a01 = zz, a02 = zz, a10 = zz, a11 = zz, a12 = zz;
#define P1K(VA, VB, KI) { \
            float4 f0 = ld4(&sF[KI][j0]); float4 f1 = ld4(&sF[KI][j0 + 4]); float4 f2 = ld4(&sF[KI][j0 + 8]); \
            fma4(a00, VA, f0); fma4(a01, VA, f1); fma4(a02, VA, f2); \
            fma4(a10, VB, f0); fma4(a11, VB, f1); fma4(a12, VB, f2); }
            #pragma unroll
            for (int k0 = 0; k0 < NS; k0 += 4) {
                float4 va = ld4(&sV[i0][k0]);
                float4 vb = ld4(&sV[i0 + 1][k0]);
                P1K(va.x, vb.x, k0 + 0)
                P1K(va.y, vb.y, k0 + 1)
                P1K(va.z, vb.z, k0 + 2)
                P1K(va.w, vb.w, k0 + 3)
            }
#undef P1K
            st4(&sW[i0][j0], a00); st4(&sW[i0][j0 + 4], a01); st4(&sW[i0][j0 + 8], a02);
            st4(&sW[i0 + 1][j0], a10); st4(&sW[i0 + 1][j0 + 4], a11); st4(&sW[i0 + 1][j0 + 8], a12);
        } else if (wv == 1 && lane < NS) {
            float a = sv[lane];
            #pragma unroll
            for (int k0 = 0; k0 < NS; k0 += 4)
                a += dot4(ld4(&sV[lane][k0]), ld4(&sc1[k0]));
            sz[lane] = a;
        }
        __syncthreads();

        // ---- Phase 2: tid<72: Qt = Qg + F^T W (4x8 tiles); wave2: qt ----
        if (tid < 72) {
            const int rg = tid / 6, cg = tid % 6;
            const int i0 = rg * 4, j0 = cg * 8;
            float4 b00 = ld4(&sQg[(i0 + 0) * NSC + j0]), b01 = ld4(&sQg[(i0 + 0) * NSC + j0 + 4]);
            float4 b10 = ld4(&sQg[(i0 + 1) * NSC + j0]), b11 = ld4(&sQg[(i0 + 1) * NSC + j0 + 4]);
            float4 b20 = ld4(&sQg[(i0 + 2) * NSC + j0]), b21 = ld4(&sQg[(i0 + 2) * NSC + j0 + 4]);
            float4 b30 = ld4(&sQg[(i0 + 3) * NSC + j0]), b31 = ld4(&sQg[(i0 + 3) * NSC + j0 + 4]);
            #pragma unroll
            for (int k = 0; k < NS; ++k) {
                float4 f = ld4(&sF[k][i0]);
                float4 w0 = ld4(&sW[k][j0]), w1 = ld4(&sW[k][j0 + 4]);
                fma4(b00, f.x, w0); fma4(b01, f.x, w1);
                fma4(b10, f.y, w0); fma4(b11, f.y, w1);
                fma4(b20, f.z, w0); fma4(b21, f.z, w1);
                fma4(b30, f.w, w0); fma4(b31, f.w, w1);
            }
            st4(&sQt[i0 + 0][j0], b00); st4(&sQt[i0 + 0][j0 + 4], b01);
            st4(&sQt[i0 + 1][j0], b10); st4(&sQt[i0 + 1][j0 + 4], b11);
            st4(&sQt[i0 + 2][j0], b20); st4(&sQt[i0 + 2][j0 + 4], b21);
            st4(&sQt[i0 + 3][j0], b30); st4(&sQt[i0 + 3][j0 + 4], b31);
        } else if (wv == 2 && lane < NSC) {
            const float* pg = p + ((size_t)b * T + t) * NSC;
            float a = pg[lane];
            for (int k = 0; k < NS; ++k) a = fmaf(sF[k][lane], sz[k], a);
            sqt[lane] = a;
        }
        __syncthreads();

        // ---- Phase 3: wave0: in-register Gauss-Jordan; waves2-3: prefetch next Q ----
        if (wv == 0) {
            float R[NC];
            if (lane < NC) {
                #pragma unroll
                for (int i = 0; i < NC; ++i) R[i] = sQt[NS + i][NS + lane];
            } else if (lane < NSC) {
                #pragma unroll
                for (int i = 0; i < NC; ++i) R[i] = sQt[NS + i][lane - NC];
            } else if (lane == NSC) {
                #pragma unroll
                for (int i = 0; i < NC; ++i) R[i] = sqt[NS + i];
            } else {
                #pragma unroll
                for (int i = 0; i < NC; ++i) R[i] = 0.f;
            }
            #pragma unroll
            for (int k = 0; k < NC; ++k) {
                float pk = __shfl(R[k], k, 64);
                float inv = 1.0f / pk;
                float tm = R[k] * inv;
                #pragma unroll
                for (int i = 0; i < NC; ++i) {
                    if (i == k) continue;
                    float cki = __shfl(R[i], k, 64);
                    R[i] = fmaf(-tm, cki, R[i]);
                }
                R[k] = tm;
            }
            if (lane >= NC && lane < NSC) {
                const int c = lane - NC;
                #pragma unroll
                for (int i = 0; i < NC; ++i) sKt[i][c] = -R[i];
            } else if (lane == NSC) {
                #pragma unroll
                for (int i = 0; i < NC; ++i) skt[i] = -R[i];
            }
        } else if (wv >= 2 && t > 0) {
            const float4* Qn = (const float4*)(Q + ((size_t)b * T + (t - 1)) * NSC * NSC);
            float4* dst = (float4*)sQg;
            for (int r = tid - 128; r < 576; r += 128) dst[r] = Qn[r];
        }
        __syncthreads();

        // ---- Phase 4: wave0: V = Qxx + Qxu K; wave1: K->global; wave2: v; wave3: k->global ----
        if (wv == 0) {
            const int i0 = (lane >> 2) * 2, j0 = (lane & 3) * 8;
            float4 a00 = ld4(&sQt[i0][j0]),     a01 = ld4(&sQt[i0][j0 + 4]);
            float4 a10 = ld4(&sQt[i0 + 1][j0]), a11 = ld4(&sQt[i0 + 1][j0 + 4]);
            #pragma unroll
            for (int k = 0; k < NC; ++k) {
                float q0 = sQt[NS + k][i0];       // Qux[k][i0] == Qxu[i0][k]
                float q1 = sQt[NS + k][i0 + 1];
                float4 k0 = ld4(&sKt[k][j0]), k1 = ld4(&sKt[k][j0 + 4]);
                fma4(a00, q0, k0); fma4(a01, q0, k1);
                fma4(a10, q1, k0); fma4(a11, q1, k1);
            }
            st4(&sV[i0][j0], a00); st4(&sV[i0][j0 + 4], a01);
            st4(&sV[i0 + 1][j0], a10); st4(&sV[i0 + 1][j0 + 4], a11);
        } else if (wv == 1) {
            float* Kg = Kws + ((size_t)b * T + t) * NC * NS;
            #pragma unroll
            for (int r = lane; r < 128; r += 64)
                ((float4*)Kg)[r] = ld4(&sKt[r >> 3][(r & 7) * 4]);
        } else if (wv == 2 && lane < NS) {
            float a = sqt[lane];
            #pragma unroll
            for (int k = 0; k < NC; ++k) a = fmaf(sQt[NS + k][lane], skt[k], a);
            sv[lane] = a;
        } else if (wv == 3 && lane < NC) {
            kws[((size_t)b * T + t) * NC + lane] = skt[lane];
        }
        __syncthreads();
    }

    // ---------- forward rollout ----------
    float xreg = (tid < NS) ? x_init[(size_t)b * NS + tid] : 0.f;
    float costAcc = 0.f;

    for (int t = 0; t < T; ++t) {
        const float* Kg = Kws + ((size_t)b * T + t) * NC * NS;
        if (tid < 128) {
            float4 kv = ((const float4*)Kg)[tid];
            st4(&sKt[tid >> 3][(tid & 7) * 4], kv);
        } else if (tid < 144) {
            skt[tid - 128] = kws[((size_t)b * T + t) * NC + (tid - 128)];
        }
        if (tid < NS) sx[tid] = xreg;
        __syncthreads();

        if (tid < NC) {
            float u = skt[tid];
            #pragma unroll
            for (int j = 0; j < NS; j += 4) u += dot4(ld4(&sKt[tid][j]), ld4(&sx[j]));
            sx[NS + tid] = u;
        }
        __syncthreads();

        const float4* Qg4 = (const float4*)(Q + ((size_t)b * T + t) * NSC * NSC);
        const float* pg = p + ((size_t)b * T + t) * NSC;
        for (int r = tid; r < 576; r += 256) {
            float4 qv = Qg4[r];
            int i = r / 12, j0 = (r % 12) * 4;
            float4 xv = ld4(&sx[j0]);
            costAcc += 0.5f * sx[i] * (qv.x * xv.x + qv.y * xv.y + qv.z * xv.z + qv.w * xv.w);
        }
        if (tid < NSC) costAcc += pg[tid] * sx[tid];
        if (tid < NS) out_x[((size_t)b * T + t) * NS + tid] = sx[tid];
        else if (tid < NSC) out_u[((size_t)b * T + t) * NC + (tid - NS)] = sx[tid];
        if (tid < NS) {
            float a = sc1[tid];
            #pragma unroll
            for (int j = 0; j < NSC; j += 4) a += dot4(ld4(&sF[tid][j]), ld4(&sx[j]));
            xreg = a;
        }
        __syncthreads();
    }

    for (int off = 32; off > 0; off >>= 1)
        costAcc += __shfl_down(costAcc, off, 64);
    if ((tid & 63) == 0) sred[wv] = costAcc;
    __syncthreads();
    if (tid == 0) out_cost[b] = (sred[0] + sred[1]) + (sred[2] + sred[3]);
}

extern "C" void kernel_launch(void* const* d_in, const int* in_sizes, int n_in,
                              void* d_out, int out_size, void* d_ws, size_t ws_size,
                              hipStream_t stream) {
    const float* x_init = (const float*)d_in[0];
    const float* Q      = (const float*)d_in[1];
    const float* p      = (const float*)d_in[2];
    const float* A      = (const float*)d_in[3];
    const float* Bm     = (const float*)d_in[4];
    const float* c1     = (const float*)d_in[5];

    float* out      = (float*)d_out;
    float* out_x    = out;
    float* out_u    = out + (size_t)NB * T * NS;
    float* out_cost = out + (size_t)NB * T * (NS + NC);

    float* Kws = (float*)d_ws;
    float* kws = Kws + (size_t)NB * T * NC * NS;

    lqr_kernel<<<NB, 256, 0, stream>>>(x_init, Q, p, A, Bm, c1,
                                       out_x, out_u, out_cost, Kws, kws);
}

// Round 3
// 1709.883 us; speedup vs baseline: 2.0384x; 1.2089x over previous
//
#include <hip/hip_runtime.h>

#define NB 512
#define T 128
#define NS 32
#define NC 16
#define NSC 48
#define PF 52   // pad stride for sF, sW, sQt (208 B rows, 16B-aligned)
#define PV 36   // pad stride for sV
#define PK 36   // pad stride for sKt / staged K rows

__device__ __forceinline__ float4 ld4(const float* p) { return *(const float4*)p; }
__device__ __forceinline__ void st4(float* p, float4 v) { *(float4*)p = v; }
__device__ __forceinline__ void fma4(float4& a, float s, float4 f) {
    a.x = fmaf(s, f.x, a.x); a.y = fmaf(s, f.y, a.y);
    a.z = fmaf(s, f.z, a.z); a.w = fmaf(s, f.w, a.w);
}
__device__ __forceinline__ float dot4(float4 a, float4 b) {
    return fmaf(a.x, b.x, fmaf(a.y, b.y, fmaf(a.z, b.z, a.w * b.w)));
}

// ================= backward Riccati kernel =================
// One block (256 threads) per batch element. 4 barriers per step.
__global__ __launch_bounds__(256, 2)
void lqr_backward(const float* __restrict__ Q,
                  const float* __restrict__ p,
                  const float* __restrict__ A,
                  const float* __restrict__ Bm,
                  const float* __restrict__ c1,
                  float* __restrict__ Kws,
                  float* __restrict__ kws)
{
    const int b = blockIdx.x;
    const int tid = threadIdx.x;
    const int lane = tid & 63;
    const int wv = tid >> 6;

    __shared__ __align__(16) float sF[NS][PF];
    __shared__ __align__(16) float sW[NS][PF];
    __shared__ __align__(16) float sQt[NSC][PF];
    __shared__ __align__(16) float sV[NS][PV];
    __shared__ __align__(16) float sKt[NC][PK];
    __shared__ __align__(16) float sz[NS];
    __shared__ __align__(16) float sqt[NSC];
    __shared__ __align__(16) float sv[NS];
    __shared__ __align__(16) float sc1[NS];
    __shared__ __align__(16) float skt[NC];

    for (int e = tid; e < NS * NSC; e += 256) {
        int i = e / NSC, j = e % NSC;
        sF[i][j] = (j < NS) ? A[(size_t)b * NS * NS + i * NS + j]
                            : Bm[(size_t)b * NS * NC + i * NC + (j - NS)];
    }
    for (int e = tid; e < NS * NS; e += 256) sV[e >> 5][e & 31] = 0.f;
    if (tid < NS) { sv[tid] = 0.f; sc1[tid] = c1[(size_t)b * NS + tid]; }
    __syncthreads();

    for (int t = T - 1; t >= 0; --t) {
        const float* Qg = Q + ((size_t)b * T + t) * NSC * NSC;

        // ---- Phase A: W = V@F (tid 0..191, 2x4 tiles); z (tid 192..223);
        //      prefetch B-phase Q rows (tid 0..95) and p (tid 96..143) ----
        float4 qgb0 = {0,0,0,0}, qgb1 = {0,0,0,0};
        float preg = 0.f;
        if (tid < 96) {
            int i0b = NS + (tid / 12) * 2, j0b = (tid % 12) * 4;
            qgb0 = ld4(Qg + i0b * NSC + j0b);
            qgb1 = ld4(Qg + (i0b + 1) * NSC + j0b);
        }
        if (tid >= 96 && tid < 144) preg = p[((size_t)b * T + t) * NSC + (tid - 96)];
        if (tid < 192) {
            const int i0 = (tid / 12) * 2, j0 = (tid % 12) * 4;
            float4 a0 = {0,0,0,0}, a1 = {0,0,0,0};
            #pragma unroll 8
            for (int k = 0; k < NS; ++k) {
                float2 v2 = *(const float2*)&sV[k][i0];   // V symmetric: V[i0..i0+1][k]
                float4 f4 = ld4(&sF[k][j0]);
                fma4(a0, v2.x, f4); fma4(a1, v2.y, f4);
            }
            st4(&sW[i0][j0], a0); st4(&sW[i0 + 1][j0], a1);
        } else if (tid < 224) {
            int i = tid - 192;
            float a = sv[i];
            #pragma unroll
            for (int k0 = 0; k0 < NS; k0 += 4)
                a += dot4(ld4(&sV[i][k0]), ld4(&sc1[k0]));
            sz[i] = a;
        }
        __syncthreads();

        // ---- Phase B: Qt rows 32..47 (Quu|Qux) (tid 0..95, 2x4 tiles);
        //      qt = p + F^T z (tid 96..143); prefetch C-phase Q (tid 64..191) ----
        float4 qgc0 = {0,0,0,0}, qgc1 = {0,0,0,0};
        int i0c = 0, j0c = 0;
        if (tid >= 64 && tid < 192) {
            int ct = tid - 64; i0c = (ct / 8) * 2; j0c = (ct % 8) * 4;
            qgc0 = ld4(Qg + i0c * NSC + j0c);
            qgc1 = ld4(Qg + (i0c + 1) * NSC + j0c);
        }
        if (tid < 96) {
            const int i0b = NS + (tid / 12) * 2, j0b = (tid % 12) * 4;
            float4 a0 = qgb0, a1 = qgb1;
            #pragma unroll 8
            for (int k = 0; k < NS; ++k) {
                float2 f2 = *(const float2*)&sF[k][i0b];
                float4 w4 = ld4(&sW[k][j0b]);
                fma4(a0, f2.x, w4); fma4(a1, f2.y, w4);
            }
            st4(&sQt[i0b][j0b], a0); st4(&sQt[i0b + 1][j0b], a1);
        } else if (tid < 144) {
            int j = tid - 96;
            float a = preg;
            #pragma unroll 8
            for (int k = 0; k < NS; ++k) a = fmaf(sF[k][j], sz[k], a);
            sqt[j] = a;
        }
        __syncthreads();

        // ---- Phase C: wave0: in-register Gauss-Jordan; tid 64..191: Qxx tiles ----
        if (wv == 0) {
            float R[NC];
            if (lane < NC) {
                #pragma unroll
                for (int i = 0; i < NC; ++i) R[i] = sQt[NS + i][NS + lane];
            } else if (lane < NSC) {
                #pragma unroll
                for (int i = 0; i < NC; ++i) R[i] = sQt[NS + i][lane - NC];
            } else if (lane == NSC) {
                #pragma unroll
                for (int i = 0; i < NC; ++i) R[i] = sqt[NS + i];
            } else {
                #pragma unroll
                for (int i = 0; i < NC; ++i) R[i] = 0.f;
            }
            #pragma unroll
            for (int k = 0; k < NC; ++k) {
                float pk = __shfl(R[k], k, 64);
                float inv = 1.0f / pk;
                float tm = R[k] * inv;
                #pragma unroll
                for (int i = 0; i < NC; ++i) {
                    if (i == k) continue;
                    float cki = __shfl(R[i], k, 64);
                    R[i] = fmaf(-tm, cki, R[i]);
                }
                R[k] = tm;
            }
            if (lane >= NC && lane < NSC) {
                const int c = lane - NC;
                #pragma unroll
                for (int i = 0; i < NC; ++i) sKt[i][c] = -R[i];
            } else if (lane == NSC) {
                #pragma unroll
                for (int i = 0; i < NC; ++i) skt[i] = -R[i];
            }
        } else if (tid < 192) {
            float4 a0 = qgc0, a1 = qgc1;
            #pragma unroll 8
            for (int k = 0; k < NS; ++k) {
                float2 f2 = *(const float2*)&sF[k][i0c];
                float4 w4 = ld4(&sW[k][j0c]);
                fma4(a0, f2.x, w4); fma4(a1, f2.y, w4);
            }
            st4(&sQt[i0c][j0c], a0); st4(&sQt[i0c + 1][j0c], a1);
        }
        __syncthreads();

        // ---- Phase D: V = Qxx + Qxu@K (tid 0..127); v (128..159);
        //      k->ws (160..175); K->ws (192..255) ----
        if (tid < 128) {
            const int i0 = (tid / 8) * 2, j0 = (tid % 8) * 4;
            float4 a0 = ld4(&sQt[i0][j0]), a1 = ld4(&sQt[i0 + 1][j0]);
            #pragma unroll
            for (int k = 0; k < NC; ++k) {
                float2 q2 = *(const float2*)&sQt[NS + k][i0];  // Qxu[i][k] = Qux[k][i]
                float4 k4 = ld4(&sKt[k][j0]);
                fma4(a0, q2.x, k4); fma4(a1, q2.y, k4);
            }
            st4(&sV[i0][j0], a0); st4(&sV[i0 + 1][j0], a1);
        } else if (tid < 160) {
            int j = tid - 128;
            float a = sqt[j];
            #pragma unroll
            for (int k = 0; k < NC; ++k) a = fmaf(sQt[NS + k][j], skt[k], a);
            sv[j] = a;
        } else if (tid < 176) {
            kws[((size_t)b * T + t) * NC + (tid - 160)] = skt[tid - 160];
        } else if (tid >= 192) {
            float4* Kg4 = (float4*)(Kws + ((size_t)b * T + t) * NC * NS);
            int e = (tid - 192) * 2;
            Kg4[e]     = ld4(&sKt[e >> 3][(e & 7) * 4]);
            Kg4[e + 1] = ld4(&sKt[(e + 1) >> 3][((e + 1) & 7) * 4]);
        }
        __syncthreads();
    }
}

// ================= forward rollout kernel =================
// wave0: serial x/u chain via shuffles (no barriers on chain), 8-step chunks;
// waves1-3: stage next K chunk + consume previous chunk (cost, outputs).
__global__ __launch_bounds__(256, 2)
void lqr_forward(const float* __restrict__ x_init,
                 const float* __restrict__ Q,
                 const float* __restrict__ p,
                 const float* __restrict__ A,
                 const float* __restrict__ Bm,
                 const float* __restrict__ c1,
                 const float* __restrict__ Kws,
                 const float* __restrict__ kws,
                 float* __restrict__ out_x,
                 float* __restrict__ out_u,
                 float* __restrict__ out_cost)
{
    const int b = blockIdx.x;
    const int tid = threadIdx.x;
    const int lane = tid & 63;
    const int wv = tid >> 6;

    __shared__ __align__(16) float sK[2][8 * 576];   // [s][row][36] padded
    __shared__ __align__(16) float sk[2][128];       // [s][16]
    __shared__ __align__(16) float sxu[2][8][48];
    __shared__ float sred[4];

    float costAcc = 0.f;
    float4 Freg[12];
    float c1reg = 0.f, xu = 0.f;

    if (wv == 0) {
        const int i = lane & 31;               // all lanes load (avoid undef regs)
        const float* Ar = A + (size_t)b * NS * NS + i * NS;
        const float* Br = Bm + (size_t)b * NS * NC + i * NC;
        #pragma unroll
        for (int g = 0; g < 8; ++g) Freg[g] = ld4(Ar + g * 4);
        #pragma unroll
        for (int g = 0; g < 4; ++g) Freg[8 + g] = ld4(Br + g * 4);
        c1reg = c1[(size_t)b * NS + i];
        xu = x_init[(size_t)b * NS + i];
    } else {
        // preload K,k chunk 0 into buffer 0
        const float4* src = (const float4*)(Kws + (size_t)b * T * NC * NS);
        int ct = tid - 64;
        for (int idx = ct; idx < 1024; idx += 192) {
            int s = idx >> 7, rem = idx & 127, row = rem >> 3, jg = rem & 7;
            st4(&sK[0][s * 576 + row * 36 + jg * 4], src[idx]);
        }
        if (ct < 32) st4(&sk[0][ct * 4], ((const float4*)(kws + (size_t)b * T * NC))[ct]);
    }
    __syncthreads();

    for (int it = 0; it <= 16; ++it) {
        if (wv == 0) {
            if (it < 16) {
                const int buf = it & 1;
                for (int s = 0; s < 8; ++s) {
                    // K row for this lane (lanes 0..31 read redundantly - harmless)
                    const float* kb = &sK[buf][s * 576 + (lane & 15) * 36];
                    float4 Kq[8];
                    #pragma unroll
                    for (int g = 0; g < 8; ++g) Kq[g] = ld4(kb + g * 4);
                    float ktv = sk[buf][s * 16 + (lane & 15)];

                    float u0 = 0.f, u1 = 0.f;
                    #pragma unroll
                    for (int g = 0; g < 8; ++g) {
                        float x0 = __shfl(xu, 4 * g + 0, 64);
                        float x1 = __shfl(xu, 4 * g + 1, 64);
                        float x2 = __shfl(xu, 4 * g + 2, 64);
                        float x3 = __shfl(xu, 4 * g + 3, 64);
                        u0 = fmaf(Kq[g].x, x0, u0); u1 = fmaf(Kq[g].y, x1, u1);
                        u0 = fmaf(Kq[g].z, x2, u0); u1 = fmaf(Kq[g].w, x3, u1);
                    }
                    if (lane >= NS && lane < NSC) xu = u0 + u1 + ktv;
                    if (lane < NSC) sxu[buf][s][lane] = xu;

                    float a0 = 0.f, a1 = 0.f;
                    #pragma unroll
                    for (int g = 0; g < 12; ++g) {
                        float x0 = __shfl(xu, 4 * g + 0, 64);
                        float x1 = __shfl(xu, 4 * g + 1, 64);
                        float x2 = __shfl(xu, 4 * g + 2, 64);
                        float x3 = __shfl(xu, 4 * g + 3, 64);
                        a0 = fmaf(Freg[g].x, x0, a0); a1 = fmaf(Freg[g].y, x1, a1);
                        a0 = fmaf(Freg[g].z, x2, a0); a1 = fmaf(Freg[g].w, x3, a1);
                    }
                    if (lane < NS) xu = a0 + a1 + c1reg;
                }
            }
        } else {
            const int ct = tid - 64;
            if (it < 15) {   // stage K,k chunk it+1
                const int nbuf = (it + 1) & 1;
                const float4* src = (const float4*)(Kws + ((size_t)b * T + (it + 1) * 8) * NC * NS);
                for (int idx = ct; idx < 1024; idx += 192) {
                    int s = idx >> 7, rem = idx & 127, row = rem >> 3, jg = rem & 7;
                    st4(&sK[nbuf][s * 576 + row * 36 + jg * 4], src[idx]);
                }
                if (ct < 32) st4(&sk[nbuf][ct * 4],
                                 ((const float4*)(kws + ((size_t)b * T + (it + 1) * 8) * NC))[ct]);
            }
            if (it >= 1) {   // consume chunk it-1: cost + outputs
                const int buf = (it - 1) & 1;
                const int c = it - 1;
                for (int s = 0; s < 8; ++s) {
                    const int t = c * 8 + s;
                    const float* Qg = Q + ((size_t)b * T + t) * NSC * NSC;
                    #pragma unroll
                    for (int rr0 = 0; rr0 < 3; ++rr0) {
                        int rr = ct * 3 + rr0;
                        float4 q = ld4(Qg + rr * 4);
                        int i = rr / 12, j0 = (rr % 12) * 4;
                        float4 xv = ld4(&sxu[buf][s][j0]);
                        costAcc = fmaf(0.5f * sxu[buf][s][i], dot4(q, xv), costAcc);
                    }
                    if (ct < NSC) {
                        float xuv = sxu[buf][s][ct];
                        costAcc = fmaf(p[((size_t)b * T + t) * NSC + ct], xuv, costAcc);
                        if (ct < NS) out_x[((size_t)b * T + t) * NS + ct] = xuv;
                        else         out_u[((size_t)b * T + t) * NC + (ct - NS)] = xuv;
                    }
                }
            }
        }
        __syncthreads();
    }

    for (int off = 32; off > 0; off >>= 1)
        costAcc += __shfl_down(costAcc, off, 64);
    if ((tid & 63) == 0) sred[wv] = costAcc;
    __syncthreads();
    if (tid == 0) out_cost[b] = (sred[0] + sred[1]) + (sred[2] + sred[3]);
}

extern "C" void kernel_launch(void* const* d_in, const int* in_sizes, int n_in,
                              void* d_out, int out_size, void* d_ws, size_t ws_size,
                              hipStream_t stream) {
    const float* x_init = (const float*)d_in[0];
    const float* Q      = (const float*)d_in[1];
    const float* p      = (const float*)d_in[2];
    const float* A      = (const float*)d_in[3];
    const float* Bm     = (const float*)d_in[4];
    const float* c1     = (const float*)d_in[5];

    float* out      = (float*)d_out;
    float* out_x    = out;
    float* out_u    = out + (size_t)NB * T * NS;
    float* out_cost = out + (size_t)NB * T * (NS + NC);

    float* Kws = (float*)d_ws;
    float* kws = Kws + (size_t)NB * T * NC * NS;

    lqr_backward<<<NB, 256, 0, stream>>>(Q, p, A, Bm, c1, Kws, kws);
    lqr_forward<<<NB, 256, 0, stream>>>(x_init, Q, p, A, Bm, c1, Kws, kws,
                                        out_x, out_u, out_cost);
}